// Round 16
// baseline (296.282 us; speedup 1.0000x reference)
//
#include <hip/hip_runtime.h>
#include <math.h>

#define HDIM 4096
#define NBLK 128
#define RNK  4
#define TOPK 3

typedef float f4 __attribute__((ext_vector_type(4)));
typedef float f2 __attribute__((ext_vector_type(2)));
typedef unsigned int u32;
typedef u32 u4 __attribute__((ext_vector_type(4)));

// fp8 e4m3 (OCP on gfx950) pack/unpack via native ops
__device__ __forceinline__ u32 pk_fp8(f4 v) {
    u32 w = (u32)__builtin_amdgcn_cvt_pk_fp8_f32(v.x, v.y, 0, false);
    w = (u32)__builtin_amdgcn_cvt_pk_fp8_f32(v.z, v.w, (int)w, true);
    return w;
}
__device__ __forceinline__ f2 upk_fp8(u32 w, bool hi) {
    typedef float vf2 __attribute__((ext_vector_type(2)));
    vf2 r = hi ? __builtin_amdgcn_cvt_pk_f32_fp8((int)w, true)
               : __builtin_amdgcn_cvt_pk_f32_fp8((int)w, false);
    f2 o; o.x = r.x; o.y = r.y; return o;
}

// ---- preprocessing (VERBATIM r10, passed): A -> fp8 e4m3, same order ----
__global__ __launch_bounds__(256) void convert_A8(
    const float* __restrict__ A, u32* __restrict__ Af8)
{
    int d = blockIdx.x * 256 + threadIdx.x;            // u4 index 0..131071
    const f4* src = reinterpret_cast<const f4*>(A) + 4 * (size_t)d;
    f4 r0 = __builtin_nontemporal_load(src + 0);
    f4 r1 = __builtin_nontemporal_load(src + 1);
    f4 r2 = __builtin_nontemporal_load(src + 2);
    f4 r3 = __builtin_nontemporal_load(src + 3);
    u4 o;
    o.x = pk_fp8(r0); o.y = pk_fp8(r1); o.z = pk_fp8(r2); o.w = pk_fp8(r3);
    reinterpret_cast<u4*>(Af8)[d] = o;
}

// 512 THREADS per token (one WG). Halves each thread's share of every phase
// (shorter per-WG critical path; a CU fills its wave slots with only 4 WGs).
// Numerics:
//  - coords/top-3/gates: BIT-EXACT r10. All 512 threads stage h->LDS; after
//    a barrier threads 0..255 recompute coords reading h_lds[tid+k*256] --
//    same values, same FMA order, same shfl trees, same redc finalize.
//  - z: split over 512 threads (2 chunks/thread, r10 inner decode order),
//    8-wave redz reduce. Order change = smooth error only (r12-validated).
//  - out = (h_lds - temb) + delta (r12/r15-validated).
__global__ __launch_bounds__(512) void npl_fused(
    const float* __restrict__ x,
    const int*   __restrict__ task_ids,
    const float* __restrict__ task_emb,
    const float* __restrict__ Wp,
    const float* __restrict__ bp,
    const float* __restrict__ centers,
    const u32*   __restrict__ Af8,
    const float* __restrict__ Bm,
    const float* __restrict__ scale_p,
    float* __restrict__ out,
    int S_per_batch)
{
    __shared__ float h_lds[HDIM];
    __shared__ float redc[4][4];
    __shared__ float redz[8][12];

    const int tid  = threadIdx.x;          // 0..511
    const int wid  = tid >> 6;             // 0..7
    const int lane = tid & 63;
    const int token = blockIdx.x;
    const int b = token / S_per_batch;
    const int task = task_ids[b];

    const float* xrow = x + (size_t)token * HDIM;
    const float* trow = task_emb + (size_t)task * HDIM;
    float*       orow = out + (size_t)token * HDIM;

    const f4* xr4 = reinterpret_cast<const f4*>(xrow);
    const f4* tr4 = reinterpret_cast<const f4*>(trow);
    f4*       or4 = reinterpret_cast<f4*>(orow);

    // ---- phase 0: all 512 threads stage h = x + temb into LDS (2 f4 each) ----
#pragma unroll
    for (int k = 0; k < 2; ++k) {
        int i4 = tid + k * 512;
        f4 xx = __builtin_nontemporal_load(xr4 + i4);
        f4 tt = tr4[i4];
        reinterpret_cast<f4*>(h_lds)[i4] = xx + tt;   // same expr as r10
    }
    __syncthreads();   // barrier 1 of 3

    // ---- coords partials: threads 0..255 replay r10's exact chain from LDS ----
    if (tid < 256) {
        float c0 = 0.f, c1 = 0.f, c2 = 0.f;
#pragma unroll
        for (int k = 0; k < 4; ++k) {
            int i4 = tid + k * 256;
            f4 hh = reinterpret_cast<const f4*>(h_lds)[i4];   // same bits as r10's hh
            int e = i4 * 4;
            const float* wrow = Wp + (size_t)e * 3;   // 12 consecutive floats
            c0 += hh.x * wrow[0];  c1 += hh.x * wrow[1];  c2 += hh.x * wrow[2];
            c0 += hh.y * wrow[3];  c1 += hh.y * wrow[4];  c2 += hh.y * wrow[5];
            c0 += hh.z * wrow[6];  c1 += hh.z * wrow[7];  c2 += hh.z * wrow[8];
            c0 += hh.w * wrow[9];  c1 += hh.w * wrow[10]; c2 += hh.w * wrow[11];
        }
#pragma unroll
        for (int off = 32; off; off >>= 1) {
            c0 += __shfl_down(c0, off);
            c1 += __shfl_down(c1, off);
            c2 += __shfl_down(c2, off);
        }
        if (lane == 0) { redc[wid][0] = c0; redc[wid][1] = c1; redc[wid][2] = c2; }
    }
    __syncthreads();   // barrier 2 of 3

    // ---- coords finalize: every thread, exact left-assoc sum (r10) ----
    float c0 = redc[0][0] + redc[1][0] + redc[2][0] + redc[3][0] + bp[0];
    float c1 = redc[0][1] + redc[1][1] + redc[2][1] + redc[3][1] + bp[1];
    float c2 = redc[0][2] + redc[1][2] + redc[2][2] + redc[3][2] + bp[2];

    // ---- scores for blocks `lane` and `lane+64` (r10 expression) ----
    float dx = c0 - centers[lane * 3 + 0];
    float dy = c1 - centers[lane * 3 + 1];
    float dz = c2 - centers[lane * 3 + 2];
    float v1 = -0.5f * (dx * dx + dy * dy + dz * dz);
    dx = c0 - centers[(lane + 64) * 3 + 0];
    dy = c1 - centers[(lane + 64) * 3 + 1];
    dz = c2 - centers[(lane + 64) * 3 + 2];
    float v2 = -0.5f * (dx * dx + dy * dy + dz * dz);

    // ---- top-3 (r10 3-pass loop verbatim, redundant on every wave) ----
    float tv0, tv1, tv2; int n0, n1, n2;
#pragma unroll
    for (int kk = 0; kk < TOPK; ++kk) {
        float v = v1; int idx = lane;
        if (v2 > v || (v2 == v && (lane + 64) < idx)) { v = v2; idx = lane + 64; }
#pragma unroll
        for (int off = 32; off; off >>= 1) {
            float ov = __shfl_down(v, off);
            int   oi = __shfl_down(idx, off);
            if (ov > v || (ov == v && oi < idx)) { v = ov; idx = oi; }
        }
        idx = __shfl(idx, 0);
        v   = __shfl(v, 0);
        if (kk == 0)      { tv0 = v; n0 = idx; }
        else if (kk == 1) { tv1 = v; n1 = idx; }
        else              { tv2 = v; n2 = idx; }
        if (idx == lane)      v1 = -3.0e38f;
        if (idx == lane + 64) v2 = -3.0e38f;
    }

    // ---- gates (r10 op sequence) ----
    float m  = tv0;
    float e0 = 1.0f;
    float e1 = expf(tv1 - m);
    float e2 = expf(tv2 - m);
    float inv = 1.0f / (e0 + e1 + e2);
    float s = scale_p[0];
    float g0 = e0 * inv * s;
    float g1 = e1 * inv * s;
    float g2 = e2 * inv * s;

    // ---- z_k = h @ A[n_k]: fp8 decode (r10 inner order), 2 chunks/thread ----
    float zp[TOPK][RNK];
#pragma unroll
    for (int kk = 0; kk < TOPK; ++kk)
#pragma unroll
        for (int r = 0; r < RNK; ++r) zp[kk][r] = 0.f;

#pragma unroll
    for (int kk = 0; kk < TOPK; ++kk) {
        int n = (kk == 0) ? n0 : (kk == 1) ? n1 : n2;
        const u4* Ab = reinterpret_cast<const u4*>(Af8) + (size_t)n * 1024;
#pragma unroll
        for (int k = 0; k < 2; ++k) {
            int idx = tid + k * 512;
            u4 q = Ab[idx];                                   // rows 4idx..4idx+3
            f4 hv = reinterpret_cast<const f4*>(h_lds)[idx];
            f2 p;
            p = upk_fp8(q.x, false); zp[kk][0] += hv.x * p.x; zp[kk][1] += hv.x * p.y;
            p = upk_fp8(q.x, true);  zp[kk][2] += hv.x * p.x; zp[kk][3] += hv.x * p.y;
            p = upk_fp8(q.y, false); zp[kk][0] += hv.y * p.x; zp[kk][1] += hv.y * p.y;
            p = upk_fp8(q.y, true);  zp[kk][2] += hv.y * p.x; zp[kk][3] += hv.y * p.y;
            p = upk_fp8(q.z, false); zp[kk][0] += hv.z * p.x; zp[kk][1] += hv.z * p.y;
            p = upk_fp8(q.z, true);  zp[kk][2] += hv.z * p.x; zp[kk][3] += hv.z * p.y;
            p = upk_fp8(q.w, false); zp[kk][0] += hv.w * p.x; zp[kk][1] += hv.w * p.y;
            p = upk_fp8(q.w, true);  zp[kk][2] += hv.w * p.x; zp[kk][3] += hv.w * p.y;
        }
    }
#pragma unroll
    for (int off = 32; off; off >>= 1) {
#pragma unroll
        for (int kk = 0; kk < TOPK; ++kk)
#pragma unroll
            for (int r = 0; r < RNK; ++r)
                zp[kk][r] += __shfl_down(zp[kk][r], off);
    }
    if (lane == 0) {
#pragma unroll
        for (int kk = 0; kk < TOPK; ++kk)
#pragma unroll
            for (int r = 0; r < RNK; ++r)
                redz[wid][kk * RNK + r] = zp[kk][r];
    }
    __syncthreads();   // barrier 3 of 3

    // ---- zf: every thread, left-assoc sum over 8 wave partials ----
    float zf_[12];
#pragma unroll
    for (int t = 0; t < 12; ++t)
        zf_[t] = ((((((redz[0][t] + redz[1][t]) + redz[2][t]) + redz[3][t])
                 + redz[4][t]) + redz[5][t]) + redz[6][t]) + redz[7][t];

    // ---- out = (h_lds - temb) + delta (r12 expression; nt stores) ----
#pragma unroll
    for (int k = 0; k < 2; ++k) {
        int i4 = tid + k * 512;
        int e = i4 * 4;          // all 4 elements in the same 32-block
        int bb = e >> 5;
        f4 hh = reinterpret_cast<const f4*>(h_lds)[i4];
        f4 tt = tr4[i4];
        f4 o = hh - tt;
        int kk = (bb == n0) ? 0 : (bb == n1) ? 1 : (bb == n2) ? 2 : -1;
        if (kk >= 0) {
            int nn = (kk == 0) ? n0 : (kk == 1) ? n1 : n2;
            float za = (kk == 0) ? zf_[0] : (kk == 1) ? zf_[4] : zf_[8];
            float zb = (kk == 0) ? zf_[1] : (kk == 1) ? zf_[5] : zf_[9];
            float zc = (kk == 0) ? zf_[2] : (kk == 1) ? zf_[6] : zf_[10];
            float zd = (kk == 0) ? zf_[3] : (kk == 1) ? zf_[7] : zf_[11];
            float gg = (kk == 0) ? g0 : (kk == 1) ? g1 : g2;
            const float* bm = Bm + (size_t)nn * 128;
            int c = e & 31;
            float d0 = za * bm[c + 0] + zb * bm[32 + c + 0] + zc * bm[64 + c + 0] + zd * bm[96 + c + 0];
            float d1 = za * bm[c + 1] + zb * bm[32 + c + 1] + zc * bm[64 + c + 1] + zd * bm[96 + c + 1];
            float d2 = za * bm[c + 2] + zb * bm[32 + c + 2] + zc * bm[64 + c + 2] + zd * bm[96 + c + 2];
            float d3 = za * bm[c + 3] + zb * bm[32 + c + 3] + zc * bm[64 + c + 3] + zd * bm[96 + c + 3];
            o.x += d0 * gg;
            o.y += d1 * gg;
            o.z += d2 * gg;
            o.w += d3 * gg;
        }
        __builtin_nontemporal_store(o, or4 + i4);
    }
}

extern "C" void kernel_launch(void* const* d_in, const int* in_sizes, int n_in,
                              void* d_out, int out_size, void* d_ws, size_t ws_size,
                              hipStream_t stream) {
    const float* x        = (const float*)d_in[0];
    const int*   task_ids = (const int*)  d_in[1];
    const float* task_emb = (const float*)d_in[2];
    const float* Wp       = (const float*)d_in[3];
    const float* bp       = (const float*)d_in[4];
    const float* centers  = (const float*)d_in[5];
    const float* A        = (const float*)d_in[6];
    const float* Bm       = (const float*)d_in[7];
    const float* scale    = (const float*)d_in[8];

    int tokens = in_sizes[0] / HDIM;   // B*S
    int B      = in_sizes[1];
    int S      = tokens / B;

    u32* Af8 = (u32*)d_ws;             // 2 MiB (ws >= 4 MiB proven earlier)

    const int n_u4 = NBLK * HDIM * RNK / 16;     // 131072 u4s
    convert_A8<<<dim3(n_u4 / 256), dim3(256), 0, stream>>>(A, Af8);
    npl_fused<<<dim3(tokens), dim3(512), 0, stream>>>(
        x, task_ids, task_emb, Wp, bp, centers, Af8, Bm, scale,
        (float*)d_out, S);
}

// Round 17
// 196.108 us; speedup vs baseline: 1.5108x; 1.5108x over previous
//
#include <hip/hip_runtime.h>
#include <math.h>

#define HDIM 4096
#define NBLK 128
#define RNK  4
#define TOPK 3

typedef float f4 __attribute__((ext_vector_type(4)));
typedef float f2 __attribute__((ext_vector_type(2)));
typedef unsigned int u32;
typedef u32 u4 __attribute__((ext_vector_type(4)));

// fp8 e4m3 (OCP on gfx950) pack/unpack via native ops
__device__ __forceinline__ u32 pk_fp8(f4 v) {
    u32 w = (u32)__builtin_amdgcn_cvt_pk_fp8_f32(v.x, v.y, 0, false);
    w = (u32)__builtin_amdgcn_cvt_pk_fp8_f32(v.z, v.w, (int)w, true);
    return w;
}
__device__ __forceinline__ f2 upk_fp8(u32 w, bool hi) {
    typedef float vf2 __attribute__((ext_vector_type(2)));
    vf2 r = hi ? __builtin_amdgcn_cvt_pk_f32_fp8((int)w, true)
               : __builtin_amdgcn_cvt_pk_f32_fp8((int)w, false);
    f2 o; o.x = r.x; o.y = r.y; return o;
}

// ---- preprocessing: A [NB][H][RNK] fp32 -> fp8 e4m3, SAME element order ----
// 2 MiB total (half an XCD L2) for the z-phase re-reads.
__global__ __launch_bounds__(256) void convert_A8(
    const float* __restrict__ A, u32* __restrict__ Af8)
{
    int d = blockIdx.x * 256 + threadIdx.x;            // u4 index 0..131071
    const f4* src = reinterpret_cast<const f4*>(A) + 4 * (size_t)d;
    f4 r0 = __builtin_nontemporal_load(src + 0);
    f4 r1 = __builtin_nontemporal_load(src + 1);
    f4 r2 = __builtin_nontemporal_load(src + 2);
    f4 r3 = __builtin_nontemporal_load(src + 3);
    u4 o;
    o.x = pk_fp8(r0); o.y = pk_fp8(r1); o.z = pk_fp8(r2); o.w = pk_fp8(r3);
    reinterpret_cast<u4*>(Af8)[d] = o;
}

// ROUND-10 KERNEL, RESTORED VERBATIM (best measured: 196.7 us, absmax 0.03125).
// One workgroup (256 threads) per token, fully fused:
// h = x + temb -> LDS; coords (fp32, wave trees + left-assoc finalize);
// scores vs 128 centers; 3-pass top-3 (wave-redundant); softmax gates;
// z = h @ A[n_k] with fp8 in-loop decode (L2-resident 2 MiB table);
// out = x + gate*z@Bm, x kept in registers, nt loads/stores on x/out.
__global__ __launch_bounds__(256) void npl_fused(
    const float* __restrict__ x,
    const int*   __restrict__ task_ids,
    const float* __restrict__ task_emb,
    const float* __restrict__ Wp,
    const float* __restrict__ bp,
    const float* __restrict__ centers,
    const u32*   __restrict__ Af8,
    const float* __restrict__ Bm,
    const float* __restrict__ scale_p,
    float* __restrict__ out,
    int S_per_batch)
{
    __shared__ float h_lds[HDIM];
    __shared__ float redc[4][4];
    __shared__ float redz[4][12];

    const int tid  = threadIdx.x;
    const int wid  = tid >> 6;
    const int lane = tid & 63;
    const int token = blockIdx.x;
    const int b = token / S_per_batch;
    const int task = task_ids[b];

    const float* xrow = x + (size_t)token * HDIM;
    const float* trow = task_emb + (size_t)task * HDIM;
    float*       orow = out + (size_t)token * HDIM;

    const f4* xr4 = reinterpret_cast<const f4*>(xrow);
    const f4* tr4 = reinterpret_cast<const f4*>(trow);
    f4*       or4 = reinterpret_cast<f4*>(orow);

    // ---- phase 1: stage h to LDS, x in regs, coords partials ----
    f4 xv[4];
    float c0 = 0.f, c1 = 0.f, c2 = 0.f;
#pragma unroll
    for (int k = 0; k < 4; ++k) {
        int i4 = tid + k * 256;
        f4 xx = __builtin_nontemporal_load(xr4 + i4);
        f4 tt = tr4[i4];
        xv[k] = xx;
        f4 hh = xx + tt;
        reinterpret_cast<f4*>(h_lds)[i4] = hh;
        int e = i4 * 4;
        const float* wrow = Wp + (size_t)e * 3;   // 12 consecutive floats
        c0 += hh.x * wrow[0];  c1 += hh.x * wrow[1];  c2 += hh.x * wrow[2];
        c0 += hh.y * wrow[3];  c1 += hh.y * wrow[4];  c2 += hh.y * wrow[5];
        c0 += hh.z * wrow[6];  c1 += hh.z * wrow[7];  c2 += hh.z * wrow[8];
        c0 += hh.w * wrow[9];  c1 += hh.w * wrow[10]; c2 += hh.w * wrow[11];
    }
#pragma unroll
    for (int off = 32; off; off >>= 1) {
        c0 += __shfl_down(c0, off);
        c1 += __shfl_down(c1, off);
        c2 += __shfl_down(c2, off);
    }
    if (lane == 0) { redc[wid][0] = c0; redc[wid][1] = c1; redc[wid][2] = c2; }
    __syncthreads();   // barrier 1 of 2

    // ---- coords finalize: every thread, exact left-assoc sum ----
    c0 = redc[0][0] + redc[1][0] + redc[2][0] + redc[3][0] + bp[0];
    c1 = redc[0][1] + redc[1][1] + redc[2][1] + redc[3][1] + bp[1];
    c2 = redc[0][2] + redc[1][2] + redc[2][2] + redc[3][2] + bp[2];

    // ---- scores for blocks `lane` and `lane+64` ----
    float dx = c0 - centers[lane * 3 + 0];
    float dy = c1 - centers[lane * 3 + 1];
    float dz = c2 - centers[lane * 3 + 2];
    float v1 = -0.5f * (dx * dx + dy * dy + dz * dz);
    dx = c0 - centers[(lane + 64) * 3 + 0];
    dy = c1 - centers[(lane + 64) * 3 + 1];
    dz = c2 - centers[(lane + 64) * 3 + 2];
    float v2 = -0.5f * (dx * dx + dy * dy + dz * dz);

    // ---- top-3 (3-pass, wave-redundant; tie -> lowest index) ----
    float tv0, tv1, tv2; int n0, n1, n2;
#pragma unroll
    for (int kk = 0; kk < TOPK; ++kk) {
        float v = v1; int idx = lane;
        if (v2 > v || (v2 == v && (lane + 64) < idx)) { v = v2; idx = lane + 64; }
#pragma unroll
        for (int off = 32; off; off >>= 1) {
            float ov = __shfl_down(v, off);
            int   oi = __shfl_down(idx, off);
            if (ov > v || (ov == v && oi < idx)) { v = ov; idx = oi; }
        }
        idx = __shfl(idx, 0);
        v   = __shfl(v, 0);
        if (kk == 0)      { tv0 = v; n0 = idx; }
        else if (kk == 1) { tv1 = v; n1 = idx; }
        else              { tv2 = v; n2 = idx; }
        if (idx == lane)      v1 = -3.0e38f;
        if (idx == lane + 64) v2 = -3.0e38f;
    }

    // ---- gates ----
    float m  = tv0;
    float e0 = 1.0f;
    float e1 = expf(tv1 - m);
    float e2 = expf(tv2 - m);
    float inv = 1.0f / (e0 + e1 + e2);
    float s = scale_p[0];
    float g0 = e0 * inv * s;
    float g1 = e1 * inv * s;
    float g2 = e2 * inv * s;

    // ---- z_k = h @ A[n_k]: fp8 table, in-loop decode, h fp32 from LDS ----
    float zp[TOPK][RNK];
#pragma unroll
    for (int kk = 0; kk < TOPK; ++kk)
#pragma unroll
        for (int r = 0; r < RNK; ++r) zp[kk][r] = 0.f;

#pragma unroll
    for (int kk = 0; kk < TOPK; ++kk) {
        int n = (kk == 0) ? n0 : (kk == 1) ? n1 : n2;
        const u4* Ab = reinterpret_cast<const u4*>(Af8) + (size_t)n * 1024;
#pragma unroll
        for (int k = 0; k < 4; ++k) {
            int idx = tid + k * 256;
            u4 q = Ab[idx];                                   // rows 4idx..4idx+3
            f4 hv = reinterpret_cast<const f4*>(h_lds)[idx];
            f2 p;
            p = upk_fp8(q.x, false); zp[kk][0] += hv.x * p.x; zp[kk][1] += hv.x * p.y;
            p = upk_fp8(q.x, true);  zp[kk][2] += hv.x * p.x; zp[kk][3] += hv.x * p.y;
            p = upk_fp8(q.y, false); zp[kk][0] += hv.y * p.x; zp[kk][1] += hv.y * p.y;
            p = upk_fp8(q.y, true);  zp[kk][2] += hv.y * p.x; zp[kk][3] += hv.y * p.y;
            p = upk_fp8(q.z, false); zp[kk][0] += hv.z * p.x; zp[kk][1] += hv.z * p.y;
            p = upk_fp8(q.z, true);  zp[kk][2] += hv.z * p.x; zp[kk][3] += hv.z * p.y;
            p = upk_fp8(q.w, false); zp[kk][0] += hv.w * p.x; zp[kk][1] += hv.w * p.y;
            p = upk_fp8(q.w, true);  zp[kk][2] += hv.w * p.x; zp[kk][3] += hv.w * p.y;
        }
    }
#pragma unroll
    for (int off = 32; off; off >>= 1) {
#pragma unroll
        for (int kk = 0; kk < TOPK; ++kk)
#pragma unroll
            for (int r = 0; r < RNK; ++r)
                zp[kk][r] += __shfl_down(zp[kk][r], off);
    }
    if (lane == 0) {
#pragma unroll
        for (int kk = 0; kk < TOPK; ++kk)
#pragma unroll
            for (int r = 0; r < RNK; ++r)
                redz[wid][kk * RNK + r] = zp[kk][r];
    }
    __syncthreads();   // barrier 2 of 2

    // ---- zf: every thread, left-assoc cross-wave sum ----
    float zf_[12];
#pragma unroll
    for (int t = 0; t < 12; ++t)
        zf_[t] = redz[0][t] + redz[1][t] + redz[2][t] + redz[3][t];

    // ---- out = x + delta (delta recomputed in-register) ----
#pragma unroll
    for (int k = 0; k < 4; ++k) {
        int i4 = tid + k * 256;
        int e = i4 * 4;          // all 4 elements in the same 32-block
        int bb = e >> 5;
        f4 o = xv[k];
        int kk = (bb == n0) ? 0 : (bb == n1) ? 1 : (bb == n2) ? 2 : -1;
        if (kk >= 0) {
            int nn = (kk == 0) ? n0 : (kk == 1) ? n1 : n2;
            float za = (kk == 0) ? zf_[0] : (kk == 1) ? zf_[4] : zf_[8];
            float zb = (kk == 0) ? zf_[1] : (kk == 1) ? zf_[5] : zf_[9];
            float zc = (kk == 0) ? zf_[2] : (kk == 1) ? zf_[6] : zf_[10];
            float zd = (kk == 0) ? zf_[3] : (kk == 1) ? zf_[7] : zf_[11];
            float gg = (kk == 0) ? g0 : (kk == 1) ? g1 : g2;
            const float* bm = Bm + (size_t)nn * 128;
            int c = e & 31;
            float d0 = za * bm[c + 0] + zb * bm[32 + c + 0] + zc * bm[64 + c + 0] + zd * bm[96 + c + 0];
            float d1 = za * bm[c + 1] + zb * bm[32 + c + 1] + zc * bm[64 + c + 1] + zd * bm[96 + c + 1];
            float d2 = za * bm[c + 2] + zb * bm[32 + c + 2] + zc * bm[64 + c + 2] + zd * bm[96 + c + 2];
            float d3 = za * bm[c + 3] + zb * bm[32 + c + 3] + zc * bm[64 + c + 3] + zd * bm[96 + c + 3];
            o.x += d0 * gg;
            o.y += d1 * gg;
            o.z += d2 * gg;
            o.w += d3 * gg;
        }
        __builtin_nontemporal_store(o, or4 + i4);
    }
}

extern "C" void kernel_launch(void* const* d_in, const int* in_sizes, int n_in,
                              void* d_out, int out_size, void* d_ws, size_t ws_size,
                              hipStream_t stream) {
    const float* x        = (const float*)d_in[0];
    const int*   task_ids = (const int*)  d_in[1];
    const float* task_emb = (const float*)d_in[2];
    const float* Wp       = (const float*)d_in[3];
    const float* bp       = (const float*)d_in[4];
    const float* centers  = (const float*)d_in[5];
    const float* A        = (const float*)d_in[6];
    const float* Bm       = (const float*)d_in[7];
    const float* scale    = (const float*)d_in[8];

    int tokens = in_sizes[0] / HDIM;   // B*S
    int B      = in_sizes[1];
    int S      = tokens / B;

    u32* Af8 = (u32*)d_ws;             // 2 MiB (ws >= 4 MiB proven earlier)

    const int n_u4 = NBLK * HDIM * RNK / 16;     // 131072 u4s
    convert_A8<<<dim3(n_u4 / 256), dim3(256), 0, stream>>>(A, Af8);
    npl_fused<<<dim3(tokens), dim3(256), 0, stream>>>(
        x, task_ids, task_emb, Wp, bp, centers, Af8, Bm, scale,
        (float*)d_out, S);
}